// Round 6
// baseline (486.940 us; speedup 1.0000x reference)
//
#include <hip/hip_runtime.h>

// ---------------------------------------------------------------------------
// GCN fraud detector — R16: R14 aggs restored + 2-tile GEMM blocks.
// R15 post-mortem: half-wave gather split REGRESSED (62->84us): occupancy
//   73->49%, and __shfl (ds_bpermute = LDS-pipe latency in every gather's
//   address chain) replaced wave-uniform readlane. The ~59-62us agg128 is a
//   line-fill floor for random 256B row gathers (3rd confirmation). REVERTED.
// R16 change: mfma_gemm processes TWO 64-row tiles per block (grid 1563->782)
//   — halves the per-gemm 32KB W-fragment LDS staging traffic + block ramp.
// Kept: binned 4-pass build (R11), stats1 fused into agg (R14), inline
//   rsqrtf(fill+1), W-repack folded into count.
// R12 lesson: NO cooperative grid.sync on 8 non-coherent XCDs.
// R13 lesson: no random 4B scatter into cold buffers (write-allocate 64B/line).
// 12 dispatches: count, scan, place, part2, 3x{gemm, agg+stats, stats2}, head.
// ---------------------------------------------------------------------------

typedef __attribute__((ext_vector_type(8))) short short8;
typedef __attribute__((ext_vector_type(4))) float f32x4;

#define BIN_SHIFT 7
#define BIN_NODES 128
#define CAPB 4096
#define CAP 64
#define AGB 2048  // agg grid (persistent blocks) == stats partial count
#define P1B 256   // graph-build blocks (== scan blockDim)

__device__ __forceinline__ float b2f(unsigned short u) {
    return __uint_as_float(((unsigned)u) << 16);
}
__device__ __forceinline__ unsigned short f2bf(float f) {
    unsigned u = __float_as_uint(f);
    return (unsigned short)((u + 0x7fff + ((u >> 16) & 1)) >> 16);
}

// --- build pass 1: per-block per-bin counts (no atomics) + W repack fold ---
__global__ __launch_bounds__(256) void count_kernel(
    const int* __restrict__ eidx, int E, int nbins, int chunk,
    int* __restrict__ cntG,
    const float* __restrict__ w0, const float* __restrict__ w1,
    const float* __restrict__ w2, unsigned short* __restrict__ wf) {
    __shared__ int cntS[1024];
    int tid = threadIdx.x;
    for (int b = tid; b < 1024; b += 256) cntS[b] = 0;

    // folded W repack: fp32 -> bf16 B-fragment order (40960 elems, blocks 0..159)
    int tg = blockIdx.x * 256 + tid;
    if (tg < 40960) {
        const float* w;
        int idx, C;
        if (tg < 16384) { w = w0; idx = tg; C = 128; }
        else if (tg < 32768) { w = w1; idx = tg - 16384; C = 128; }
        else { w = w2; idx = tg - 32768; C = 64; }
        int j = idx & 7;
        int lane = (idx >> 3) & 63;
        int q = (idx >> 9) & 3;
        int n_tile = idx >> 11;
        int k = q * 32 + (lane >> 4) * 8 + j;
        int n = n_tile * 16 + (lane & 15);
        wf[tg] = f2bf(w[k * C + n]);
    }
    __syncthreads();
    int e0 = blockIdx.x * chunk;
    int e1 = min(e0 + chunk, E);
    for (int e = e0 + tid; e < e1; e += 256)
        atomicAdd(&cntS[eidx[E + e] >> BIN_SHIFT], 1);
    __syncthreads();
    for (int b = tid; b < nbins; b += 256)
        cntG[b * P1B + blockIdx.x] = cntS[b];
}

// --- build pass 2: per-bin exclusive prefix over P1B block counts ---
__global__ __launch_bounds__(P1B) void scan_kernel(int* __restrict__ cntG,
                                                   int* __restrict__ bin_fill) {
    __shared__ int sh[P1B];
    int b = blockIdx.x, t = threadIdx.x;
    int v = cntG[b * P1B + t];
    sh[t] = v;
    __syncthreads();
    for (int d = 1; d < P1B; d <<= 1) {
        int u = (t >= d) ? sh[t - d] : 0;
        __syncthreads();
        sh[t] += u;
        __syncthreads();
    }
    cntG[b * P1B + t] = sh[t] - v;  // exclusive base, in place
    if (t == P1B - 1) bin_fill[b] = sh[P1B - 1];
}

// --- build pass 3: place edges, packed (src<<7 | dst&127), LDS atomics only ---
__global__ __launch_bounds__(256) void place_kernel(
    const int* __restrict__ eidx, int E, int nbins, int chunk,
    const int* __restrict__ baseG, int* __restrict__ binned) {
    __shared__ int cntS[1024];
    __shared__ int baseS[1024];
    int tid = threadIdx.x;
    for (int b = tid; b < nbins; b += 256) {
        baseS[b] = baseG[b * P1B + blockIdx.x];
        cntS[b] = 0;
    }
    __syncthreads();
    int e0 = blockIdx.x * chunk;
    int e1 = min(e0 + chunk, E);
    for (int e = e0 + tid; e < e1; e += 256) {
        int d = eidx[E + e];
        int s = eidx[e];
        int b = d >> BIN_SHIFT;
        int p = baseS[b] + atomicAdd(&cntS[b], 1);
        if (p < CAPB) binned[b * CAPB + p] = (s << BIN_SHIFT) | (d & (BIN_NODES - 1));
    }
}

// --- build pass 4: block per bin; LDS slot assignment; L2-local stage writes ---
__global__ __launch_bounds__(256) void part2_kernel(const int* __restrict__ bin_fill,
                                                    const int* __restrict__ binned,
                                                    int N, int* __restrict__ fill,
                                                    int* __restrict__ stage) {
    __shared__ int lfill[BIN_NODES];
    int b = blockIdx.x, tid = threadIdx.x;
    if (tid < BIN_NODES) lfill[tid] = 0;
    __syncthreads();
    int cnt = min(bin_fill[b], CAPB);
    const int* seg = binned + b * CAPB;
    for (int i = tid; i < cnt; i += 256) {
        int v = seg[i];
        int dl = v & (BIN_NODES - 1);
        int p = atomicAdd(&lfill[dl], 1);
        int node = (b << BIN_SHIFT) + dl;
        if (p < CAP) stage[(node << 6) + p] = v >> BIN_SHIFT;
    }
    __syncthreads();
    if (tid < BIN_NODES) {
        int node = (b << BIN_SHIFT) + tid;
        if (node < N) fill[node] = lfill[tid];
    }
}

__device__ __forceinline__ void load8(const float* p, float4& lo, float4& hi) {
    lo = *(const float4*)p;
    hi = *(const float4*)(p + 4);
}
__device__ __forceinline__ void load8(const unsigned short* p, float4& lo, float4& hi) {
    int4 q = *(const int4*)p;
    lo = make_float4(__uint_as_float((unsigned)q.x << 16),
                     __uint_as_float((unsigned)q.x & 0xffff0000u),
                     __uint_as_float((unsigned)q.y << 16),
                     __uint_as_float((unsigned)q.y & 0xffff0000u));
    hi = make_float4(__uint_as_float((unsigned)q.z << 16),
                     __uint_as_float((unsigned)q.z & 0xffff0000u),
                     __uint_as_float((unsigned)q.w << 16),
                     __uint_as_float((unsigned)q.w & 0xffff0000u));
}

// --- MFMA GEMM: out[N x C](bf16) = dis_row * (relu(xin*scale+shift) @ W) ---
// R16: each block computes TWO 64-row tiles with one W staging.
template <int C, typename InT>
__global__ __launch_bounds__(256, 5) void mfma_gemm_kernel(
    const InT* __restrict__ xin, const unsigned short* __restrict__ wf,
    const float* __restrict__ scale, const float* __restrict__ shift,
    const int* __restrict__ fill, unsigned short* __restrict__ out, int N) {
    constexpr int NT = C / 16;
    constexpr int WFRAGS = NT * 4 * 64;
    __shared__ short8 ws[WFRAGS];
    int tid = threadIdx.x;
    for (int i = tid; i < WFRAGS; i += 256) ws[i] = ((const short8*)wf)[i];

    int lane = tid & 63;
    int wave = tid >> 6;
    int r15 = lane & 15, r4 = lane >> 4;
    int ntiles = (N + 63) >> 6;
    __syncthreads();

#pragma unroll
    for (int rep = 0; rep < 2; rep++) {
        int tile = blockIdx.x * 2 + rep;
        if (tile >= ntiles) break;
        int m0 = tile * 64 + wave * 16;
        f32x4 acc[NT];
#pragma unroll
        for (int t = 0; t < NT; t++) acc[t] = (f32x4){0.f, 0.f, 0.f, 0.f};
        int row0c = min(m0 + r15, N - 1);

#pragma unroll
        for (int q = 0; q < 4; q++) {
            int kb = q * 32 + r4 * 8;
            float4 a0l, a0h;
            load8(xin + (size_t)row0c * 128 + kb, a0l, a0h);
            if (scale) {
                float4 scl = *(const float4*)&scale[kb];
                float4 sch = *(const float4*)&scale[kb + 4];
                float4 shl = *(const float4*)&shift[kb];
                float4 shh = *(const float4*)&shift[kb + 4];
                a0l.x = fmaxf(a0l.x * scl.x + shl.x, 0.f);
                a0l.y = fmaxf(a0l.y * scl.y + shl.y, 0.f);
                a0l.z = fmaxf(a0l.z * scl.z + shl.z, 0.f);
                a0l.w = fmaxf(a0l.w * scl.w + shl.w, 0.f);
                a0h.x = fmaxf(a0h.x * sch.x + shh.x, 0.f);
                a0h.y = fmaxf(a0h.y * sch.y + shh.y, 0.f);
                a0h.z = fmaxf(a0h.z * sch.z + shh.z, 0.f);
                a0h.w = fmaxf(a0h.w * sch.w + shh.w, 0.f);
            }
            short8 a0;
            a0[0] = (short)f2bf(a0l.x); a0[1] = (short)f2bf(a0l.y);
            a0[2] = (short)f2bf(a0l.z); a0[3] = (short)f2bf(a0l.w);
            a0[4] = (short)f2bf(a0h.x); a0[5] = (short)f2bf(a0h.y);
            a0[6] = (short)f2bf(a0h.z); a0[7] = (short)f2bf(a0h.w);
#pragma unroll
            for (int nt = 0; nt < NT; nt++) {
                short8 b = ws[(nt * 4 + q) * 64 + lane];
                acc[nt] = __builtin_amdgcn_mfma_f32_16x16x32_bf16(a0, b, acc[nt], 0, 0, 0);
            }
        }
        float d0r[4];
#pragma unroll
        for (int r = 0; r < 4; r++) {
            int rowa = m0 + r4 * 4 + r;
            d0r[r] = (rowa < N) ? rsqrtf((float)fill[rowa] + 1.0f) : 0.f;
        }
#pragma unroll
        for (int nt = 0; nt < NT; nt++) {
            int col = nt * 16 + r15;
#pragma unroll
            for (int r = 0; r < 4; r++) {
                int rowa = m0 + r4 * 4 + r;
                if (rowa < N) out[(size_t)rowa * C + col] = f2bf(acc[nt][r] * d0r[r]);
            }
        }
    }
}

// --- agg C=128 + fused BN-stats: persistent grid-stride, wave per node ---
// (R14-exact gather loops: readlane broadcast, ushort2 rows, 16 in flight.)
__global__ __launch_bounds__(256) void agg128s_kernel(
    const unsigned short* __restrict__ h, const int* __restrict__ fill,
    const int* __restrict__ stage, unsigned short* __restrict__ out,
    float* __restrict__ partials, int N) {
    int lane = threadIdx.x & 63;
    int wave = threadIdx.x >> 6;
    int ngroups = (N + 3) >> 2;
    float2 s = make_float2(0.f, 0.f), qq = make_float2(0.f, 0.f);
    for (int g = blockIdx.x; g < ngroups; g += gridDim.x) {
        int node = g * 4 + wave;
        bool valid = node < N;
        int nodec = valid ? node : 0;
        float dn = rsqrtf((float)fill[nodec] + 1.0f);
        ushort2 sv = ((const ushort2*)(h + (size_t)nodec * 128))[lane];
        float2 acc = make_float2(b2f(sv.x), b2f(sv.y));
        int ne = valid ? min(fill[nodec], CAP) : 0;
        int pk = (lane < ne) ? stage[(nodec << 6) + lane] : 0;
        int j = 0;
        for (; j + 16 <= ne; j += 16) {
            ushort2 a[16];
#pragma unroll
            for (int t = 0; t < 16; t++) {
                int src = __builtin_amdgcn_readlane(pk, j + t);
                a[t] = ((const ushort2*)(h + (size_t)src * 128))[lane];
            }
#pragma unroll
            for (int t = 0; t < 16; t++) { acc.x += b2f(a[t].x); acc.y += b2f(a[t].y); }
        }
        for (; j + 8 <= ne; j += 8) {
            ushort2 a[8];
#pragma unroll
            for (int t = 0; t < 8; t++) {
                int src = __builtin_amdgcn_readlane(pk, j + t);
                a[t] = ((const ushort2*)(h + (size_t)src * 128))[lane];
            }
#pragma unroll
            for (int t = 0; t < 8; t++) { acc.x += b2f(a[t].x); acc.y += b2f(a[t].y); }
        }
        for (; j + 4 <= ne; j += 4) {
            ushort2 a[4];
#pragma unroll
            for (int t = 0; t < 4; t++) {
                int src = __builtin_amdgcn_readlane(pk, j + t);
                a[t] = ((const ushort2*)(h + (size_t)src * 128))[lane];
            }
#pragma unroll
            for (int t = 0; t < 4; t++) { acc.x += b2f(a[t].x); acc.y += b2f(a[t].y); }
        }
        for (; j < ne; j++) {
            int src = __builtin_amdgcn_readlane(pk, j);
            ushort2 a = ((const ushort2*)(h + (size_t)src * 128))[lane];
            acc.x += b2f(a.x);
            acc.y += b2f(a.y);
        }
        if (valid) {
            unsigned short rx = f2bf(acc.x * dn), ry = f2bf(acc.y * dn);
            ((ushort2*)(out + (size_t)node * 128))[lane] = make_ushort2(rx, ry);
            float fx = b2f(rx), fy = b2f(ry);
            s.x += fx; s.y += fy;
            qq.x += fx * fx; qq.y += fy * fy;
        }
    }
    // block reduce: channel ch=2*lane(+1); partials[blk][0..127]=sum,[128..255]=sumsq
    __shared__ float red[4][256];
    red[wave][2 * lane] = s.x;
    red[wave][2 * lane + 1] = s.y;
    red[wave][128 + 2 * lane] = qq.x;
    red[wave][128 + 2 * lane + 1] = qq.y;
    __syncthreads();
    int t = threadIdx.x;
    partials[(size_t)blockIdx.x * 256 + t] =
        red[0][t] + red[1][t] + red[2][t] + red[3][t];
}

// --- agg C=64 + fused BN-stats: wave per node, half-wave even/odd edges ---
__global__ __launch_bounds__(256) void agg64s_kernel(
    const unsigned short* __restrict__ h, const int* __restrict__ fill,
    const int* __restrict__ stage, unsigned short* __restrict__ out,
    float* __restrict__ partials, int N) {
    int lane = threadIdx.x & 63;
    int wave = threadIdx.x >> 6;
    int half = lane >> 5, ch = lane & 31;
    int ngroups = (N + 3) >> 2;
    float2 s = make_float2(0.f, 0.f), qq = make_float2(0.f, 0.f);
    for (int g = blockIdx.x; g < ngroups; g += gridDim.x) {
        int node = g * 4 + wave;
        bool valid = node < N;
        int nodec = valid ? node : 0;
        float dn = rsqrtf((float)fill[nodec] + 1.0f);
        float2 acc = make_float2(0.f, 0.f);
        if (half == 0) {
            ushort2 sv = ((const ushort2*)(h + (size_t)nodec * 64))[ch];
            acc.x = b2f(sv.x);
            acc.y = b2f(sv.y);
        }
        int ne = valid ? min(fill[nodec], CAP) : 0;
        int pk = (lane < ne) ? stage[(nodec << 6) + lane] : 0;
        int j = 0;
        for (; j + 16 <= ne; j += 16) {
            ushort2 a[8];
#pragma unroll
            for (int t = 0; t < 8; t++) {
                int src = __shfl(pk, j + 2 * t + half);
                a[t] = ((const ushort2*)(h + (size_t)src * 64))[ch];
            }
#pragma unroll
            for (int t = 0; t < 8; t++) { acc.x += b2f(a[t].x); acc.y += b2f(a[t].y); }
        }
        for (; j + 8 <= ne; j += 8) {
            ushort2 a[4];
#pragma unroll
            for (int t = 0; t < 4; t++) {
                int src = __shfl(pk, j + 2 * t + half);
                a[t] = ((const ushort2*)(h + (size_t)src * 64))[ch];
            }
#pragma unroll
            for (int t = 0; t < 4; t++) { acc.x += b2f(a[t].x); acc.y += b2f(a[t].y); }
        }
        for (; j < ne; j += 2) {
            int jj = j + half;
            int src = __shfl(pk, jj);
            bool v = jj < ne;
            ushort2 a = ((const ushort2*)(h + (size_t)src * 64))[ch];
            acc.x += v ? b2f(a.x) : 0.f;
            acc.y += v ? b2f(a.y) : 0.f;
        }
        acc.x += __shfl_down(acc.x, 32);
        acc.y += __shfl_down(acc.y, 32);
        if (valid && half == 0) {
            unsigned short rx = f2bf(acc.x * dn), ry = f2bf(acc.y * dn);
            ((ushort2*)(out + (size_t)node * 64))[ch] = make_ushort2(rx, ry);
            float fx = b2f(rx), fy = b2f(ry);
            s.x += fx; s.y += fy;
            qq.x += fx * fx; qq.y += fy * fy;
        }
    }
    // block reduce: half0 lanes own channels 2*ch(+1); [0..63]=sum,[64..127]=sumsq
    __shared__ float red[4][128];
    if (half == 0) {
        red[wave][2 * ch] = s.x;
        red[wave][2 * ch + 1] = s.y;
        red[wave][64 + 2 * ch] = qq.x;
        red[wave][64 + 2 * ch + 1] = qq.y;
    }
    __syncthreads();
    int t = threadIdx.x;
    if (t < 128)
        partials[(size_t)blockIdx.x * 128 + t] =
            red[0][t] + red[1][t] + red[2][t] + red[3][t];
}

// --- BN stats stage 2 (+finalize): block per channel, reduce AGB partials ---
template <int C>
__global__ __launch_bounds__(256) void stats2_kernel(const float* __restrict__ partials,
                                                     const float* __restrict__ g,
                                                     const float* __restrict__ be, int N,
                                                     int nparts, float* __restrict__ scale,
                                                     float* __restrict__ shift) {
    int c = blockIdx.x;
    int t = threadIdx.x;
    float s = 0.f, q = 0.f;
    for (int b = t; b < nparts; b += 256) {
        const float* pb = partials + (size_t)b * 2 * C;
        s += pb[c];
        q += pb[C + c];
    }
    __shared__ float rs[256], rq[256];
    rs[t] = s;
    rq[t] = q;
    __syncthreads();
    for (int d = 128; d > 0; d >>= 1) {
        if (t < d) {
            rs[t] += rs[t + d];
            rq[t] += rq[t + d];
        }
        __syncthreads();
    }
    if (t == 0) {
        float inv_n = 1.0f / (float)N;
        float mean = rs[0] * inv_n;
        float var = rq[0] * inv_n - mean * mean;
        var = var > 0.f ? var : 0.f;
        float sc = g[c] * rsqrtf(var + 1e-5f);
        scale[c] = sc;
        shift[c] = be[c] - mean * sc;
    }
}

__global__ __launch_bounds__(256) void head_kernel(
    const unsigned short* __restrict__ h, const float* __restrict__ scale,
    const float* __restrict__ shift, const float* __restrict__ wc1,
    const float* __restrict__ bc1, const float* __restrict__ wc2,
    const float* __restrict__ bc2, float* __restrict__ out, int N) {
    __shared__ float w1s[64 * 32];
    __shared__ float b1s[32], w2s[32], s2s[64], sh2[64];
    __shared__ float b2s;
    int tid = threadIdx.x;
    for (int i = tid; i < 64 * 32; i += 256) w1s[i] = wc1[i];
    if (tid < 32) { b1s[tid] = bc1[tid]; w2s[tid] = wc2[tid]; }
    if (tid < 64) { s2s[tid] = scale[tid]; sh2[tid] = shift[tid]; }
    if (tid == 0) b2s = bc2[0];
    __syncthreads();
    int n = blockIdx.x * 256 + tid;
    if (n >= N) return;
    float v[64];
#pragma unroll
    for (int k = 0; k < 64; k++) {
        float x = b2f(h[(size_t)n * 64 + k]) * s2s[k] + sh2[k];
        v[k] = x > 0.f ? x : 0.f;
    }
    float o = b2s;
#pragma unroll 2
    for (int j = 0; j < 32; j++) {
        float t = b1s[j];
#pragma unroll
        for (int k = 0; k < 64; k++) t += v[k] * w1s[k * 32 + j];
        t = t > 0.f ? t : 0.f;
        o += t * w2s[j];
    }
    out[n] = o;
}

extern "C" void kernel_launch(void* const* d_in, const int* in_sizes, int n_in,
                              void* d_out, int out_size, void* d_ws, size_t ws_size,
                              hipStream_t stream) {
    const float* x = (const float*)d_in[0];
    const int* eidx = (const int*)d_in[1];
    const float* w0 = (const float*)d_in[2];
    const float* g0 = (const float*)d_in[4];
    const float* be0 = (const float*)d_in[5];
    const float* w1 = (const float*)d_in[6];
    const float* g1 = (const float*)d_in[8];
    const float* be1 = (const float*)d_in[9];
    const float* w2 = (const float*)d_in[10];
    const float* g2 = (const float*)d_in[12];
    const float* be2 = (const float*)d_in[13];
    const float* wc1 = (const float*)d_in[14];
    const float* bc1 = (const float*)d_in[15];
    const float* wc2 = (const float*)d_in[16];
    const float* bc2 = (const float*)d_in[17];

    const int N = in_sizes[0] / 128;
    const int E = in_sizes[1] / 2;
    const int nbins = (N + BIN_NODES - 1) >> BIN_SHIFT;

    char* p = (char*)d_ws;
    auto alloc = [&](size_t bytes) {
        void* r = (void*)p;
        p += (bytes + 255) & ~(size_t)255;
        return r;
    };
    int* bin_fill = (int*)alloc((size_t)nbins * 4);
    int* fill = (int*)alloc((size_t)N * 4);
    int* binned = (int*)alloc((size_t)nbins * CAPB * 4);
    int* stage = (int*)alloc((size_t)N * CAP * 4);
    float* ss = (float*)alloc(3 * 256 * 4);
    float* partials = (float*)alloc((size_t)AGB * 256 * 4);
    unsigned short* hA = (unsigned short*)alloc((size_t)N * 128 * 2);
    unsigned short* hB = (unsigned short*)alloc((size_t)N * 128 * 2);
    unsigned short* wf = (unsigned short*)alloc(40960 * 2);
    unsigned short* wf0 = wf;
    unsigned short* wf1 = wf + 16384;
    unsigned short* wf2 = wf + 32768;

    float* sc0 = ss, *sh0 = ss + 128;
    float* sc1 = ss + 256, *sh1 = ss + 384;
    float* sc2 = ss + 512, *sh2 = ss + 640;

    // cntG/baseG reuse the partials buffer (nbins*P1B*4 = 800KB <= 2MB); the
    // graph build fully completes before the first agg writes partials.
    int* cntG = (int*)partials;

    // --- graph build: count -> scan -> place -> part2 (zero global atomics) ---
    int chunk = (E + P1B - 1) / P1B;
    count_kernel<<<P1B, 256, 0, stream>>>(eidx, E, nbins, chunk, cntG, w0, w1, w2, wf);
    scan_kernel<<<nbins, P1B, 0, stream>>>(cntG, bin_fill);
    place_kernel<<<P1B, 256, 0, stream>>>(eidx, E, nbins, chunk, cntG, binned);
    part2_kernel<<<nbins, 256, 0, stream>>>(bin_fill, binned, N, fill, stage);

    int ntiles = (N + 63) / 64;
    int gemm_grid = (ntiles + 1) / 2;  // 2 tiles per block

    // --- layer 0 ---
    mfma_gemm_kernel<128, float><<<gemm_grid, 256, 0, stream>>>(x, wf0, nullptr, nullptr,
                                                                fill, hA, N);
    agg128s_kernel<<<AGB, 256, 0, stream>>>(hA, fill, stage, hB, partials, N);
    stats2_kernel<128><<<128, 256, 0, stream>>>(partials, g0, be0, N, AGB, sc0, sh0);

    // --- layer 1 ---
    mfma_gemm_kernel<128, unsigned short><<<gemm_grid, 256, 0, stream>>>(
        hB, wf1, sc0, sh0, fill, hA, N);
    agg128s_kernel<<<AGB, 256, 0, stream>>>(hA, fill, stage, hB, partials, N);
    stats2_kernel<128><<<128, 256, 0, stream>>>(partials, g1, be1, N, AGB, sc1, sh1);

    // --- layer 2 (128 -> 64) ---
    mfma_gemm_kernel<64, unsigned short><<<gemm_grid, 256, 0, stream>>>(
        hB, wf2, sc1, sh1, fill, hA, N);
    agg64s_kernel<<<AGB, 256, 0, stream>>>(hA, fill, stage, hB, partials, N);
    stats2_kernel<64><<<64, 256, 0, stream>>>(partials, g2, be2, N, AGB, sc2, sh2);

    // --- head ---
    head_kernel<<<(N + 255) / 256, 256, 0, stream>>>(hB, sc2, sh2, wc1, bc1, wc2,
                                                     bc2, (float*)d_out, N);
}

// Round 7
// 421.120 us; speedup vs baseline: 1.1563x; 1.1563x over previous
//
#include <hip/hip_runtime.h>

// ---------------------------------------------------------------------------
// GCN fraud detector — R17: LDS-staged GEMM epilogue (kill write amplification).
// R16 post-mortem: GEMMs are ~63us each (42us in R14, below top-5 cutoff).
//   WRITE_SIZE 93.8MB for a 25.6MB output = 3.7x write amplification: 2B/lane
//   epilogue stores dirty each 64B line from multiple instrs/waves -> partial
//   line fills + re-dirtied evictions. MfmaUtil 1.8%, VALUBusy 5% -> the GEMM
//   is HBM-bound on junk write traffic. 2-tile/block also regressed (occupancy
//   26%, second tile serializes) -> reverted to 1 tile/block.
// R17: after MFMA, REUSE the ws LDS buffer (no extra LDS; 5 blocks/CU kept):
//   barrier -> scatter bf16 acc into LDS (stride C+8 ushorts, bank-safe,
//   16B-aligned rows) -> barrier -> coalesced short8 (16B/lane) stores, 1KB
//   contiguous per wave-instruction, zero partial lines.
// Kept: binned 4-pass build (R11), stats1 fused into agg (R14), inline
//   rsqrtf(fill+1), W-repack folded into count, R14-exact agg gather loops
//   (~59-62us line-fill floor, 3x confirmed; readlane not shfl — R15 lesson).
// R12 lesson: NO cooperative grid.sync on 8 non-coherent XCDs.
// R13 lesson: no random 4B scatter into cold buffers (write-allocate 64B/line).
// 12 dispatches: count, scan, place, part2, 3x{gemm, agg+stats, stats2}, head.
// ---------------------------------------------------------------------------

typedef __attribute__((ext_vector_type(8))) short short8;
typedef __attribute__((ext_vector_type(4))) float f32x4;

#define BIN_SHIFT 7
#define BIN_NODES 128
#define CAPB 4096
#define CAP 64
#define AGB 2048  // agg grid (persistent blocks) == stats partial count
#define P1B 256   // graph-build blocks (== scan blockDim)

__device__ __forceinline__ float b2f(unsigned short u) {
    return __uint_as_float(((unsigned)u) << 16);
}
__device__ __forceinline__ unsigned short f2bf(float f) {
    unsigned u = __float_as_uint(f);
    return (unsigned short)((u + 0x7fff + ((u >> 16) & 1)) >> 16);
}

// --- build pass 1: per-block per-bin counts (no atomics) + W repack fold ---
__global__ __launch_bounds__(256) void count_kernel(
    const int* __restrict__ eidx, int E, int nbins, int chunk,
    int* __restrict__ cntG,
    const float* __restrict__ w0, const float* __restrict__ w1,
    const float* __restrict__ w2, unsigned short* __restrict__ wf) {
    __shared__ int cntS[1024];
    int tid = threadIdx.x;
    for (int b = tid; b < 1024; b += 256) cntS[b] = 0;

    // folded W repack: fp32 -> bf16 B-fragment order (40960 elems, blocks 0..159)
    int tg = blockIdx.x * 256 + tid;
    if (tg < 40960) {
        const float* w;
        int idx, C;
        if (tg < 16384) { w = w0; idx = tg; C = 128; }
        else if (tg < 32768) { w = w1; idx = tg - 16384; C = 128; }
        else { w = w2; idx = tg - 32768; C = 64; }
        int j = idx & 7;
        int lane = (idx >> 3) & 63;
        int q = (idx >> 9) & 3;
        int n_tile = idx >> 11;
        int k = q * 32 + (lane >> 4) * 8 + j;
        int n = n_tile * 16 + (lane & 15);
        wf[tg] = f2bf(w[k * C + n]);
    }
    __syncthreads();
    int e0 = blockIdx.x * chunk;
    int e1 = min(e0 + chunk, E);
    for (int e = e0 + tid; e < e1; e += 256)
        atomicAdd(&cntS[eidx[E + e] >> BIN_SHIFT], 1);
    __syncthreads();
    for (int b = tid; b < nbins; b += 256)
        cntG[b * P1B + blockIdx.x] = cntS[b];
}

// --- build pass 2: per-bin exclusive prefix over P1B block counts ---
__global__ __launch_bounds__(P1B) void scan_kernel(int* __restrict__ cntG,
                                                   int* __restrict__ bin_fill) {
    __shared__ int sh[P1B];
    int b = blockIdx.x, t = threadIdx.x;
    int v = cntG[b * P1B + t];
    sh[t] = v;
    __syncthreads();
    for (int d = 1; d < P1B; d <<= 1) {
        int u = (t >= d) ? sh[t - d] : 0;
        __syncthreads();
        sh[t] += u;
        __syncthreads();
    }
    cntG[b * P1B + t] = sh[t] - v;  // exclusive base, in place
    if (t == P1B - 1) bin_fill[b] = sh[P1B - 1];
}

// --- build pass 3: place edges, packed (src<<7 | dst&127), LDS atomics only ---
__global__ __launch_bounds__(256) void place_kernel(
    const int* __restrict__ eidx, int E, int nbins, int chunk,
    const int* __restrict__ baseG, int* __restrict__ binned) {
    __shared__ int cntS[1024];
    __shared__ int baseS[1024];
    int tid = threadIdx.x;
    for (int b = tid; b < nbins; b += 256) {
        baseS[b] = baseG[b * P1B + blockIdx.x];
        cntS[b] = 0;
    }
    __syncthreads();
    int e0 = blockIdx.x * chunk;
    int e1 = min(e0 + chunk, E);
    for (int e = e0 + tid; e < e1; e += 256) {
        int d = eidx[E + e];
        int s = eidx[e];
        int b = d >> BIN_SHIFT;
        int p = baseS[b] + atomicAdd(&cntS[b], 1);
        if (p < CAPB) binned[b * CAPB + p] = (s << BIN_SHIFT) | (d & (BIN_NODES - 1));
    }
}

// --- build pass 4: block per bin; LDS slot assignment; L2-local stage writes ---
__global__ __launch_bounds__(256) void part2_kernel(const int* __restrict__ bin_fill,
                                                    const int* __restrict__ binned,
                                                    int N, int* __restrict__ fill,
                                                    int* __restrict__ stage) {
    __shared__ int lfill[BIN_NODES];
    int b = blockIdx.x, tid = threadIdx.x;
    if (tid < BIN_NODES) lfill[tid] = 0;
    __syncthreads();
    int cnt = min(bin_fill[b], CAPB);
    const int* seg = binned + b * CAPB;
    for (int i = tid; i < cnt; i += 256) {
        int v = seg[i];
        int dl = v & (BIN_NODES - 1);
        int p = atomicAdd(&lfill[dl], 1);
        int node = (b << BIN_SHIFT) + dl;
        if (p < CAP) stage[(node << 6) + p] = v >> BIN_SHIFT;
    }
    __syncthreads();
    if (tid < BIN_NODES) {
        int node = (b << BIN_SHIFT) + tid;
        if (node < N) fill[node] = lfill[tid];
    }
}

__device__ __forceinline__ void load8(const float* p, float4& lo, float4& hi) {
    lo = *(const float4*)p;
    hi = *(const float4*)(p + 4);
}
__device__ __forceinline__ void load8(const unsigned short* p, float4& lo, float4& hi) {
    int4 q = *(const int4*)p;
    lo = make_float4(__uint_as_float((unsigned)q.x << 16),
                     __uint_as_float((unsigned)q.x & 0xffff0000u),
                     __uint_as_float((unsigned)q.y << 16),
                     __uint_as_float((unsigned)q.y & 0xffff0000u));
    hi = make_float4(__uint_as_float((unsigned)q.z << 16),
                     __uint_as_float((unsigned)q.z & 0xffff0000u),
                     __uint_as_float((unsigned)q.w << 16),
                     __uint_as_float((unsigned)q.w & 0xffff0000u));
}

// --- MFMA GEMM: out[N x C](bf16) = dis_row * (relu(xin*scale+shift) @ W) ---
// R17: LDS-staged epilogue reusing ws; fully-coalesced 16B/lane C-writes.
template <int C, typename InT>
__global__ __launch_bounds__(256, 5) void mfma_gemm_kernel(
    const InT* __restrict__ xin, const unsigned short* __restrict__ wf,
    const float* __restrict__ scale, const float* __restrict__ shift,
    const int* __restrict__ fill, unsigned short* __restrict__ out, int N) {
    constexpr int NT = C / 16;
    constexpr int WFRAGS = NT * 4 * 64;
    constexpr int OS = C + 8;  // output stage stride (ushorts): bank-stagger, 16B-aligned
    __shared__ short8 ws[WFRAGS];  // 32KB (C=128) / 16KB (C=64); reused as outS
    int tid = threadIdx.x;
    for (int i = tid; i < WFRAGS; i += 256) ws[i] = ((const short8*)wf)[i];

    int lane = tid & 63;
    int wave = tid >> 6;
    int m0 = blockIdx.x * 64 + wave * 16;
    int r15 = lane & 15, r4 = lane >> 4;
    f32x4 acc[NT];
#pragma unroll
    for (int t = 0; t < NT; t++) acc[t] = (f32x4){0.f, 0.f, 0.f, 0.f};
    int row0c = min(m0 + r15, N - 1);
    __syncthreads();

#pragma unroll
    for (int q = 0; q < 4; q++) {
        int kb = q * 32 + r4 * 8;
        float4 a0l, a0h;
        load8(xin + (size_t)row0c * 128 + kb, a0l, a0h);
        if (scale) {
            float4 scl = *(const float4*)&scale[kb];
            float4 sch = *(const float4*)&scale[kb + 4];
            float4 shl = *(const float4*)&shift[kb];
            float4 shh = *(const float4*)&shift[kb + 4];
            a0l.x = fmaxf(a0l.x * scl.x + shl.x, 0.f);
            a0l.y = fmaxf(a0l.y * scl.y + shl.y, 0.f);
            a0l.z = fmaxf(a0l.z * scl.z + shl.z, 0.f);
            a0l.w = fmaxf(a0l.w * scl.w + shl.w, 0.f);
            a0h.x = fmaxf(a0h.x * sch.x + shh.x, 0.f);
            a0h.y = fmaxf(a0h.y * sch.y + shh.y, 0.f);
            a0h.z = fmaxf(a0h.z * sch.z + shh.z, 0.f);
            a0h.w = fmaxf(a0h.w * sch.w + shh.w, 0.f);
        }
        short8 a0;
        a0[0] = (short)f2bf(a0l.x); a0[1] = (short)f2bf(a0l.y);
        a0[2] = (short)f2bf(a0l.z); a0[3] = (short)f2bf(a0l.w);
        a0[4] = (short)f2bf(a0h.x); a0[5] = (short)f2bf(a0h.y);
        a0[6] = (short)f2bf(a0h.z); a0[7] = (short)f2bf(a0h.w);
#pragma unroll
        for (int nt = 0; nt < NT; nt++) {
            short8 b = ws[(nt * 4 + q) * 64 + lane];
            acc[nt] = __builtin_amdgcn_mfma_f32_16x16x32_bf16(a0, b, acc[nt], 0, 0, 0);
        }
    }
    float d0r[4];
#pragma unroll
    for (int r = 0; r < 4; r++) {
        int rowa = m0 + r4 * 4 + r;
        d0r[r] = (rowa < N) ? rsqrtf((float)fill[rowa] + 1.0f) : 0.f;
    }
    // ---- epilogue: stage bf16 tile in LDS (reuse ws), then coalesced store ----
    __syncthreads();  // all waves done reading ws
    unsigned short* outS = (unsigned short*)ws;
#pragma unroll
    for (int nt = 0; nt < NT; nt++) {
        int col = nt * 16 + r15;
#pragma unroll
        for (int r = 0; r < 4; r++) {
            int lrow = wave * 16 + r4 * 4 + r;
            outS[lrow * OS + col] = f2bf(acc[nt][r] * d0r[r]);
        }
    }
    __syncthreads();
    constexpr int SEGS_PER_ROW = C / 8;        // 16B segments per row
    constexpr int SEGS = 64 * SEGS_PER_ROW;    // per block
    int base = blockIdx.x * 64;
#pragma unroll
    for (int s2 = tid; s2 < SEGS; s2 += 256) {
        int lrow = s2 / SEGS_PER_ROW;
        int o8 = s2 % SEGS_PER_ROW;
        int rowa = base + lrow;
        if (rowa < N)
            *(short8*)(out + (size_t)rowa * C + o8 * 8) =
                *(const short8*)&outS[lrow * OS + o8 * 8];
    }
}

// --- agg C=128 + fused BN-stats: persistent grid-stride, wave per node ---
// (R14-exact gather loops: readlane broadcast, ushort2 rows, 16 in flight.)
__global__ __launch_bounds__(256) void agg128s_kernel(
    const unsigned short* __restrict__ h, const int* __restrict__ fill,
    const int* __restrict__ stage, unsigned short* __restrict__ out,
    float* __restrict__ partials, int N) {
    int lane = threadIdx.x & 63;
    int wave = threadIdx.x >> 6;
    int ngroups = (N + 3) >> 2;
    float2 s = make_float2(0.f, 0.f), qq = make_float2(0.f, 0.f);
    for (int g = blockIdx.x; g < ngroups; g += gridDim.x) {
        int node = g * 4 + wave;
        bool valid = node < N;
        int nodec = valid ? node : 0;
        float dn = rsqrtf((float)fill[nodec] + 1.0f);
        ushort2 sv = ((const ushort2*)(h + (size_t)nodec * 128))[lane];
        float2 acc = make_float2(b2f(sv.x), b2f(sv.y));
        int ne = valid ? min(fill[nodec], CAP) : 0;
        int pk = (lane < ne) ? stage[(nodec << 6) + lane] : 0;
        int j = 0;
        for (; j + 16 <= ne; j += 16) {
            ushort2 a[16];
#pragma unroll
            for (int t = 0; t < 16; t++) {
                int src = __builtin_amdgcn_readlane(pk, j + t);
                a[t] = ((const ushort2*)(h + (size_t)src * 128))[lane];
            }
#pragma unroll
            for (int t = 0; t < 16; t++) { acc.x += b2f(a[t].x); acc.y += b2f(a[t].y); }
        }
        for (; j + 8 <= ne; j += 8) {
            ushort2 a[8];
#pragma unroll
            for (int t = 0; t < 8; t++) {
                int src = __builtin_amdgcn_readlane(pk, j + t);
                a[t] = ((const ushort2*)(h + (size_t)src * 128))[lane];
            }
#pragma unroll
            for (int t = 0; t < 8; t++) { acc.x += b2f(a[t].x); acc.y += b2f(a[t].y); }
        }
        for (; j + 4 <= ne; j += 4) {
            ushort2 a[4];
#pragma unroll
            for (int t = 0; t < 4; t++) {
                int src = __builtin_amdgcn_readlane(pk, j + t);
                a[t] = ((const ushort2*)(h + (size_t)src * 128))[lane];
            }
#pragma unroll
            for (int t = 0; t < 4; t++) { acc.x += b2f(a[t].x); acc.y += b2f(a[t].y); }
        }
        for (; j < ne; j++) {
            int src = __builtin_amdgcn_readlane(pk, j);
            ushort2 a = ((const ushort2*)(h + (size_t)src * 128))[lane];
            acc.x += b2f(a.x);
            acc.y += b2f(a.y);
        }
        if (valid) {
            unsigned short rx = f2bf(acc.x * dn), ry = f2bf(acc.y * dn);
            ((ushort2*)(out + (size_t)node * 128))[lane] = make_ushort2(rx, ry);
            float fx = b2f(rx), fy = b2f(ry);
            s.x += fx; s.y += fy;
            qq.x += fx * fx; qq.y += fy * fy;
        }
    }
    // block reduce: channel ch=2*lane(+1); partials[blk][0..127]=sum,[128..255]=sumsq
    __shared__ float red[4][256];
    red[wave][2 * lane] = s.x;
    red[wave][2 * lane + 1] = s.y;
    red[wave][128 + 2 * lane] = qq.x;
    red[wave][128 + 2 * lane + 1] = qq.y;
    __syncthreads();
    int t = threadIdx.x;
    partials[(size_t)blockIdx.x * 256 + t] =
        red[0][t] + red[1][t] + red[2][t] + red[3][t];
}

// --- agg C=64 + fused BN-stats: wave per node, half-wave even/odd edges ---
__global__ __launch_bounds__(256) void agg64s_kernel(
    const unsigned short* __restrict__ h, const int* __restrict__ fill,
    const int* __restrict__ stage, unsigned short* __restrict__ out,
    float* __restrict__ partials, int N) {
    int lane = threadIdx.x & 63;
    int wave = threadIdx.x >> 6;
    int half = lane >> 5, ch = lane & 31;
    int ngroups = (N + 3) >> 2;
    float2 s = make_float2(0.f, 0.f), qq = make_float2(0.f, 0.f);
    for (int g = blockIdx.x; g < ngroups; g += gridDim.x) {
        int node = g * 4 + wave;
        bool valid = node < N;
        int nodec = valid ? node : 0;
        float dn = rsqrtf((float)fill[nodec] + 1.0f);
        float2 acc = make_float2(0.f, 0.f);
        if (half == 0) {
            ushort2 sv = ((const ushort2*)(h + (size_t)nodec * 64))[ch];
            acc.x = b2f(sv.x);
            acc.y = b2f(sv.y);
        }
        int ne = valid ? min(fill[nodec], CAP) : 0;
        int pk = (lane < ne) ? stage[(nodec << 6) + lane] : 0;
        int j = 0;
        for (; j + 16 <= ne; j += 16) {
            ushort2 a[8];
#pragma unroll
            for (int t = 0; t < 8; t++) {
                int src = __shfl(pk, j + 2 * t + half);
                a[t] = ((const ushort2*)(h + (size_t)src * 64))[ch];
            }
#pragma unroll
            for (int t = 0; t < 8; t++) { acc.x += b2f(a[t].x); acc.y += b2f(a[t].y); }
        }
        for (; j + 8 <= ne; j += 8) {
            ushort2 a[4];
#pragma unroll
            for (int t = 0; t < 4; t++) {
                int src = __shfl(pk, j + 2 * t + half);
                a[t] = ((const ushort2*)(h + (size_t)src * 64))[ch];
            }
#pragma unroll
            for (int t = 0; t < 4; t++) { acc.x += b2f(a[t].x); acc.y += b2f(a[t].y); }
        }
        for (; j < ne; j += 2) {
            int jj = j + half;
            int src = __shfl(pk, jj);
            bool v = jj < ne;
            ushort2 a = ((const ushort2*)(h + (size_t)src * 64))[ch];
            acc.x += v ? b2f(a.x) : 0.f;
            acc.y += v ? b2f(a.y) : 0.f;
        }
        acc.x += __shfl_down(acc.x, 32);
        acc.y += __shfl_down(acc.y, 32);
        if (valid && half == 0) {
            unsigned short rx = f2bf(acc.x * dn), ry = f2bf(acc.y * dn);
            ((ushort2*)(out + (size_t)node * 64))[ch] = make_ushort2(rx, ry);
            float fx = b2f(rx), fy = b2f(ry);
            s.x += fx; s.y += fy;
            qq.x += fx * fx; qq.y += fy * fy;
        }
    }
    // block reduce: half0 lanes own channels 2*ch(+1); [0..63]=sum,[64..127]=sumsq
    __shared__ float red[4][128];
    if (half == 0) {
        red[wave][2 * ch] = s.x;
        red[wave][2 * ch + 1] = s.y;
        red[wave][64 + 2 * ch] = qq.x;
        red[wave][64 + 2 * ch + 1] = qq.y;
    }
    __syncthreads();
    int t = threadIdx.x;
    if (t < 128)
        partials[(size_t)blockIdx.x * 128 + t] =
            red[0][t] + red[1][t] + red[2][t] + red[3][t];
}

// --- BN stats stage 2 (+finalize): block per channel, reduce AGB partials ---
template <int C>
__global__ __launch_bounds__(256) void stats2_kernel(const float* __restrict__ partials,
                                                     const float* __restrict__ g,
                                                     const float* __restrict__ be, int N,
                                                     int nparts, float* __restrict__ scale,
                                                     float* __restrict__ shift) {
    int c = blockIdx.x;
    int t = threadIdx.x;
    float s = 0.f, q = 0.f;
    for (int b = t; b < nparts; b += 256) {
        const float* pb = partials + (size_t)b * 2 * C;
        s += pb[c];
        q += pb[C + c];
    }
    __shared__ float rs[256], rq[256];
    rs[t] = s;
    rq[t] = q;
    __syncthreads();
    for (int d = 128; d > 0; d >>= 1) {
        if (t < d) {
            rs[t] += rs[t + d];
            rq[t] += rq[t + d];
        }
        __syncthreads();
    }
    if (t == 0) {
        float inv_n = 1.0f / (float)N;
        float mean = rs[0] * inv_n;
        float var = rq[0] * inv_n - mean * mean;
        var = var > 0.f ? var : 0.f;
        float sc = g[c] * rsqrtf(var + 1e-5f);
        scale[c] = sc;
        shift[c] = be[c] - mean * sc;
    }
}

__global__ __launch_bounds__(256) void head_kernel(
    const unsigned short* __restrict__ h, const float* __restrict__ scale,
    const float* __restrict__ shift, const float* __restrict__ wc1,
    const float* __restrict__ bc1, const float* __restrict__ wc2,
    const float* __restrict__ bc2, float* __restrict__ out, int N) {
    __shared__ float w1s[64 * 32];
    __shared__ float b1s[32], w2s[32], s2s[64], sh2[64];
    __shared__ float b2s;
    int tid = threadIdx.x;
    for (int i = tid; i < 64 * 32; i += 256) w1s[i] = wc1[i];
    if (tid < 32) { b1s[tid] = bc1[tid]; w2s[tid] = wc2[tid]; }
    if (tid < 64) { s2s[tid] = scale[tid]; sh2[tid] = shift[tid]; }
    if (tid == 0) b2s = bc2[0];
    __syncthreads();
    int n = blockIdx.x * 256 + tid;
    if (n >= N) return;
    float v[64];
#pragma unroll
    for (int k = 0; k < 64; k++) {
        float x = b2f(h[(size_t)n * 64 + k]) * s2s[k] + sh2[k];
        v[k] = x > 0.f ? x : 0.f;
    }
    float o = b2s;
#pragma unroll 2
    for (int j = 0; j < 32; j++) {
        float t = b1s[j];
#pragma unroll
        for (int k = 0; k < 64; k++) t += v[k] * w1s[k * 32 + j];
        t = t > 0.f ? t : 0.f;
        o += t * w2s[j];
    }
    out[n] = o;
}

extern "C" void kernel_launch(void* const* d_in, const int* in_sizes, int n_in,
                              void* d_out, int out_size, void* d_ws, size_t ws_size,
                              hipStream_t stream) {
    const float* x = (const float*)d_in[0];
    const int* eidx = (const int*)d_in[1];
    const float* w0 = (const float*)d_in[2];
    const float* g0 = (const float*)d_in[4];
    const float* be0 = (const float*)d_in[5];
    const float* w1 = (const float*)d_in[6];
    const float* g1 = (const float*)d_in[8];
    const float* be1 = (const float*)d_in[9];
    const float* w2 = (const float*)d_in[10];
    const float* g2 = (const float*)d_in[12];
    const float* be2 = (const float*)d_in[13];
    const float* wc1 = (const float*)d_in[14];
    const float* bc1 = (const float*)d_in[15];
    const float* wc2 = (const float*)d_in[16];
    const float* bc2 = (const float*)d_in[17];

    const int N = in_sizes[0] / 128;
    const int E = in_sizes[1] / 2;
    const int nbins = (N + BIN_NODES - 1) >> BIN_SHIFT;

    char* p = (char*)d_ws;
    auto alloc = [&](size_t bytes) {
        void* r = (void*)p;
        p += (bytes + 255) & ~(size_t)255;
        return r;
    };
    int* bin_fill = (int*)alloc((size_t)nbins * 4);
    int* fill = (int*)alloc((size_t)N * 4);
    int* binned = (int*)alloc((size_t)nbins * CAPB * 4);
    int* stage = (int*)alloc((size_t)N * CAP * 4);
    float* ss = (float*)alloc(3 * 256 * 4);
    float* partials = (float*)alloc((size_t)AGB * 256 * 4);
    unsigned short* hA = (unsigned short*)alloc((size_t)N * 128 * 2);
    unsigned short* hB = (unsigned short*)alloc((size_t)N * 128 * 2);
    unsigned short* wf = (unsigned short*)alloc(40960 * 2);
    unsigned short* wf0 = wf;
    unsigned short* wf1 = wf + 16384;
    unsigned short* wf2 = wf + 32768;

    float* sc0 = ss, *sh0 = ss + 128;
    float* sc1 = ss + 256, *sh1 = ss + 384;
    float* sc2 = ss + 512, *sh2 = ss + 640;

    // cntG/baseG reuse the partials buffer (nbins*P1B*4 = 800KB <= 2MB); the
    // graph build fully completes before the first agg writes partials.
    int* cntG = (int*)partials;

    // --- graph build: count -> scan -> place -> part2 (zero global atomics) ---
    int chunk = (E + P1B - 1) / P1B;
    count_kernel<<<P1B, 256, 0, stream>>>(eidx, E, nbins, chunk, cntG, w0, w1, w2, wf);
    scan_kernel<<<nbins, P1B, 0, stream>>>(cntG, bin_fill);
    place_kernel<<<P1B, 256, 0, stream>>>(eidx, E, nbins, chunk, cntG, binned);
    part2_kernel<<<nbins, 256, 0, stream>>>(bin_fill, binned, N, fill, stage);

    int gemm_grid = (N + 63) / 64;

    // --- layer 0 ---
    mfma_gemm_kernel<128, float><<<gemm_grid, 256, 0, stream>>>(x, wf0, nullptr, nullptr,
                                                                fill, hA, N);
    agg128s_kernel<<<AGB, 256, 0, stream>>>(hA, fill, stage, hB, partials, N);
    stats2_kernel<128><<<128, 256, 0, stream>>>(partials, g0, be0, N, AGB, sc0, sh0);

    // --- layer 1 ---
    mfma_gemm_kernel<128, unsigned short><<<gemm_grid, 256, 0, stream>>>(
        hB, wf1, sc0, sh0, fill, hA, N);
    agg128s_kernel<<<AGB, 256, 0, stream>>>(hA, fill, stage, hB, partials, N);
    stats2_kernel<128><<<128, 256, 0, stream>>>(partials, g1, be1, N, AGB, sc1, sh1);

    // --- layer 2 (128 -> 64) ---
    mfma_gemm_kernel<64, unsigned short><<<gemm_grid, 256, 0, stream>>>(
        hB, wf2, sc1, sh1, fill, hA, N);
    agg64s_kernel<<<AGB, 256, 0, stream>>>(hA, fill, stage, hB, partials, N);
    stats2_kernel<64><<<64, 256, 0, stream>>>(partials, g2, be2, N, AGB, sc2, sh2);

    // --- head ---
    head_kernel<<<(N + 255) / 256, 256, 0, stream>>>(hB, sc2, sh2, wc1, bc1, wc2,
                                                     bc2, (float*)d_out, N);
}